// Round 3
// baseline (322.067 us; speedup 1.0000x reference)
//
#include <hip/hip_runtime.h>
#include <stdint.h>

#define S_LEN 2048
#define NB    4
#define DMOD  1024
#define NH    16
#define HD    64

typedef float f32x4 __attribute__((ext_vector_type(4)));
typedef float f32x16 __attribute__((ext_vector_type(16)));
typedef short bf16x8 __attribute__((ext_vector_type(8)));
typedef unsigned int u32x4 __attribute__((ext_vector_type(4)));
typedef unsigned short u16;
typedef unsigned int u32;

__device__ __forceinline__ u16 f32_to_bf16(float f) {
  union { float f; unsigned int u; } v; v.f = f;
  unsigned int r = v.u + 0x7fffu + ((v.u >> 16) & 1u);  // RNE
  return (u16)(r >> 16);
}

__device__ __forceinline__ float fast_exp2(float x) {
#if __has_builtin(__builtin_amdgcn_exp2f)
  return __builtin_amdgcn_exp2f(x);
#else
  return exp2f(x);
#endif
}

typedef __attribute__((address_space(1))) const unsigned int gu32;
typedef __attribute__((address_space(3))) unsigned int lu32;
__device__ __forceinline__ void async_copy16(const void* g, void* l) {
  __builtin_amdgcn_global_load_lds((gu32*)g, (lu32*)l, 16, 0, 0);
}

// ---------------- fp32 -> bf16 weight conversion (4 weights, 1 launch) ----
__global__ __launch_bounds__(256) void convert4_kernel(const float* __restrict__ w0,
                                                       const float* __restrict__ w1,
                                                       const float* __restrict__ w2,
                                                       const float* __restrict__ w3,
                                                       u16* __restrict__ o0, u16* __restrict__ o1,
                                                       u16* __restrict__ o2, u16* __restrict__ o3) {
  const float* in; u16* out;
  switch (blockIdx.y) {
    case 0: in = w0; out = o0; break;
    case 1: in = w1; out = o1; break;
    case 2: in = w2; out = o2; break;
    default: in = w3; out = o3; break;
  }
  int i = (blockIdx.x * 256 + threadIdx.x) * 4;
  float4 v = *(const float4*)(in + i);
  ushort4 o;
  o.x = f32_to_bf16(v.x); o.y = f32_to_bf16(v.y);
  o.z = f32_to_bf16(v.z); o.w = f32_to_bf16(v.w);
  *(ushort4*)(out + i) = o;
}

// ---------------- GEMM: C = A @ W^T (+bias)*scale ----------------
// MODE 0: A = fp32 X [S][NB][D] (per-batch rows), out bf16 [bh][s][dk]
// MODE 1: same A, out bf16 TRANSPOSED [bh][dk][s]   (for V)
// MODE 2: A = bf16 [NB][S][D], out fp32 [s][b][d]   (final projection)
template <int MODE>
__global__ __launch_bounds__(256) void gemm_tpl(const void* __restrict__ Aany,
                                                const u16* __restrict__ Bw,
                                                const float* __restrict__ bias,
                                                void* __restrict__ outp,
                                                float scale) {
  __shared__ u16 a_lds[128 * 32];
  __shared__ u16 b_lds[128 * 32];
  const int tid  = threadIdx.x;
  const int wid  = tid >> 6;
  const int lane = tid & 63;
  const int wm = wid >> 1, wn = wid & 1;   // 2x2 waves, 64x64 each
  const int bz = blockIdx.z;
  const int m0 = blockIdx.x * 128;
  const int n0 = blockIdx.y * 128;

  f32x4 acc[4][4] = {};

  for (int kt = 0; kt < 32; ++kt) {
    const int k0 = kt * 32;
    __syncthreads();
    #pragma unroll
    for (int i = 0; i < 2; ++i) {
      int row = wid * 32 + i * 16 + (lane >> 2);
      int sc  = (lane & 3) ^ ((row >> 1) & 3);
      const u16* src = Bw + (size_t)(n0 + row) * 1024 + k0 + sc * 8;
      async_copy16(src, b_lds + wid * 1024 + i * 512);
    }
    if constexpr (MODE != 2) {
      int row = tid >> 1, half = tid & 1;
      const float* src = (const float*)Aany + ((size_t)(m0 + row) * NB + bz) * 1024 + k0 + half * 16;
      u16 tmp[16];
      #pragma unroll
      for (int i = 0; i < 4; ++i) {
        float4 v = *(const float4*)(src + i * 4);
        tmp[i*4+0] = f32_to_bf16(v.x); tmp[i*4+1] = f32_to_bf16(v.y);
        tmp[i*4+2] = f32_to_bf16(v.z); tmp[i*4+3] = f32_to_bf16(v.w);
      }
      #pragma unroll
      for (int c = 0; c < 2; ++c) {
        int chunk = half * 2 + c;
        int slot  = chunk ^ ((row >> 1) & 3);
        *(int4*)(a_lds + row * 32 + slot * 8) = *(const int4*)(tmp + c * 8);
      }
    } else {
      #pragma unroll
      for (int i = 0; i < 2; ++i) {
        int row = wid * 32 + i * 16 + (lane >> 2);
        int sc  = (lane & 3) ^ ((row >> 1) & 3);
        const u16* src = (const u16*)Aany + ((size_t)bz * S_LEN + m0 + row) * 1024 + k0 + sc * 8;
        async_copy16(src, a_lds + wid * 1024 + i * 512);
      }
    }
    asm volatile("s_waitcnt vmcnt(0)" ::: "memory");
    __syncthreads();

    bf16x8 af[4], bfr[4];
    #pragma unroll
    for (int mi = 0; mi < 4; ++mi) {
      int row = wm * 64 + mi * 16 + (lane & 15);
      int ch  = (lane >> 4) ^ ((row >> 1) & 3);
      af[mi] = *(const bf16x8*)(a_lds + row * 32 + ch * 8);
    }
    #pragma unroll
    for (int ni = 0; ni < 4; ++ni) {
      int row = wn * 64 + ni * 16 + (lane & 15);
      int ch  = (lane >> 4) ^ ((row >> 1) & 3);
      bfr[ni] = *(const bf16x8*)(b_lds + row * 32 + ch * 8);
    }
    __builtin_amdgcn_s_setprio(1);
    #pragma unroll
    for (int mi = 0; mi < 4; ++mi)
      #pragma unroll
      for (int ni = 0; ni < 4; ++ni)
        acc[mi][ni] = __builtin_amdgcn_mfma_f32_16x16x32_bf16(af[mi], bfr[ni], acc[mi][ni], 0, 0, 0);
    __builtin_amdgcn_s_setprio(0);
  }

  #pragma unroll
  for (int ni = 0; ni < 4; ++ni) {
    int n = n0 + wn * 64 + ni * 16 + (lane & 15);
    float bv = bias[n];
    #pragma unroll
    for (int mi = 0; mi < 4; ++mi) {
      int sbase = m0 + wm * 64 + mi * 16 + ((lane >> 4) << 2);
      if constexpr (MODE == 0) {
        u16* o = (u16*)outp;
        int h = n >> 6, dk = n & 63;
        size_t base = (size_t)(bz * NH + h) * S_LEN;
        #pragma unroll
        for (int r = 0; r < 4; ++r)
          o[(base + sbase + r) * HD + dk] = f32_to_bf16((acc[mi][ni][r] + bv) * scale);
      } else if constexpr (MODE == 1) {
        int h = n >> 6, dk = n & 63;
        size_t idx = ((size_t)(bz * NH + h) * HD + dk) * S_LEN + sbase;
        ushort4 o4;
        o4.x = f32_to_bf16((acc[mi][ni][0] + bv) * scale);
        o4.y = f32_to_bf16((acc[mi][ni][1] + bv) * scale);
        o4.z = f32_to_bf16((acc[mi][ni][2] + bv) * scale);
        o4.w = f32_to_bf16((acc[mi][ni][3] + bv) * scale);
        *(ushort4*)((u16*)outp + idx) = o4;
      } else {
        float* o = (float*)outp;
        #pragma unroll
        for (int r = 0; r < 4; ++r)
          o[((size_t)(sbase + r) * NB + bz) * 1024 + n] = acc[mi][ni][r] + bv;
      }
    }
  }
}

// ---------------- flash attention, 8-wave 32x32 swapped-QK ----------------
// SPLIT=0: full KV range, writes normalized bf16 Oatt.
// SPLIT=1: blockIdx.x = qt*2 + kvh; half KV range, writes fp32 partial acc + (m,l).
template <int SPLIT>
__global__ __launch_bounds__(512) void attn_kernel(const u16* __restrict__ Qb,
                                                   const u16* __restrict__ Kb,
                                                   const u16* __restrict__ Vt,
                                                   u16* __restrict__ Oatt,
                                                   float* __restrict__ Op,
                                                   float2* __restrict__ Ml) {
  __shared__ u16 kbuf[2][64 * 64];
  __shared__ u16 vbuf[2][64 * 64];   // V^T tile: [d=64][k=64]
  __shared__ float alds[8][32];
  const int tid = threadIdx.x;
  const int w = tid >> 6, lane = tid & 63;
  const int hi = lane >> 5, l31 = lane & 31;
  const int h = blockIdx.y, b = blockIdx.z;
  const int bh = b * NH + h;
  const int qt  = SPLIT ? (blockIdx.x >> 1) : blockIdx.x;
  const int kvh = SPLIT ? (blockIdx.x & 1) : 0;
  const int NT  = SPLIT ? 16 : 32;
  const int kv_t0 = kvh * 16;
  const int q0 = qt * 256 + w * 32;

  bf16x8 qf[4];
  {
    const u16* qp = Qb + ((size_t)bh * S_LEN + q0 + l31) * HD + hi * 8;
    #pragma unroll
    for (int s = 0; s < 4; ++s) qf[s] = *(const bf16x8*)(qp + s * 16);
  }

  f32x16 acc0 = {}, acc1 = {}, accl = {};
  float m_run = -1e30f;
  const bf16x8 ones = {(short)0x3F80, (short)0x3F80, (short)0x3F80, (short)0x3F80,
                       (short)0x3F80, (short)0x3F80, (short)0x3F80, (short)0x3F80};

  const int rl = w * 8 + (lane >> 3);
  const int cg = (lane & 7) ^ (rl & 7);
  const u16* ksrc = Kb + ((size_t)bh * S_LEN + kv_t0 * 64 + rl) * HD + cg * 8;
  const u16* vsrc = Vt + ((size_t)bh * HD + rl) * S_LEN + kv_t0 * 64 + cg * 8;

  async_copy16(ksrc, &kbuf[0][w * 512]);
  async_copy16(vsrc, &vbuf[0][w * 512]);
  asm volatile("s_waitcnt vmcnt(0)" ::: "memory");
  __syncthreads();

  for (int kb = 0; kb < NT; ++kb) {
    const int cur = kb & 1;
    if (kb + 1 < NT) {
      async_copy16(ksrc + (size_t)(kb + 1) * 64 * HD, &kbuf[cur ^ 1][w * 512]);
      async_copy16(vsrc + (kb + 1) * 64, &vbuf[cur ^ 1][w * 512]);
    }
    const u16* KL = kbuf[cur];
    const u16* VL = vbuf[cur];

    // ---- QK^T (swapped): D[k][q], col q = lane&31
    f32x16 pk0 = {}, pk1 = {};
    {
      const int rb = l31 * 64;
      const int r7 = l31 & 7;
      __builtin_amdgcn_s_setprio(1);
      #pragma unroll
      for (int s = 0; s < 4; ++s) {
        const int ch = ((2 * s + hi) ^ r7) * 8;
        bf16x8 kf0 = *(const bf16x8*)(KL + rb + ch);
        bf16x8 kf1 = *(const bf16x8*)(KL + rb + 2048 + ch);
        pk0 = __builtin_amdgcn_mfma_f32_32x32x16_bf16(kf0, qf[s], pk0, 0, 0, 0);
        pk1 = __builtin_amdgcn_mfma_f32_32x32x16_bf16(kf1, qf[s], pk1, 0, 0, 0);
      }
      __builtin_amdgcn_s_setprio(0);
    }

    // ---- online softmax, in-register (q = lane&31 domain)
    float t8[8];
    #pragma unroll
    for (int r = 0; r < 8; ++r)
      t8[r] = fmaxf(fmaxf(pk0[r], pk0[r + 8]), fmaxf(pk1[r], pk1[r + 8]));
    float pm = fmaxf(fmaxf(fmaxf(t8[0], t8[1]), fmaxf(t8[2], t8[3])),
                     fmaxf(fmaxf(t8[4], t8[5]), fmaxf(t8[6], t8[7])));
#if __has_builtin(__builtin_amdgcn_permlane32_swap)
    {
      u32 pmu = __builtin_bit_cast(u32, pm);
      auto sw = __builtin_amdgcn_permlane32_swap(pmu, pmu, false, false);
      float po = __builtin_bit_cast(float, hi ? sw[0] : sw[1]);
      pm = fmaxf(pm, po);
    }
#else
    pm = fmaxf(pm, __shfl_xor(pm, 32));
#endif

    if (!__all(pm <= m_run + 8.0f)) {   // defer-max: rescale is rare
      float mn = fmaxf(m_run, pm);
      float al = fast_exp2(m_run - mn);
      m_run = mn;
      if (lane < 32) alds[w][l31] = al;
      #pragma unroll
      for (int r = 0; r < 16; ++r) {
        float av = alds[w][(r & 3) + 8 * (r >> 2) + 4 * hi];
        acc0[r] *= av; acc1[r] *= av; accl[r] *= av;
      }
    }
    #pragma unroll
    for (int r = 0; r < 16; ++r) {
      pk0[r] = fast_exp2(pk0[r] - m_run);
      pk1[r] = fast_exp2(pk1[r] - m_run);
    }

    // ---- P -> bf16 A-fragments in-register (cvt_pk + permlane32_swap)
    u32 c0[8], c1[8];
    #pragma unroll
    for (int i = 0; i < 8; ++i) {
      float a0 = pk0[2 * i], b0 = pk0[2 * i + 1];
      float a1 = pk1[2 * i], b1 = pk1[2 * i + 1];
      asm("v_cvt_pk_bf16_f32 %0, %1, %2" : "=v"(c0[i]) : "v"(a0), "v"(b0));
      asm("v_cvt_pk_bf16_f32 %0, %1, %2" : "=v"(c1[i]) : "v"(a1), "v"(b1));
    }
    u32 pa[4][4];
#if __has_builtin(__builtin_amdgcn_permlane32_swap)
    #pragma unroll
    for (int g = 0; g < 2; ++g) {
      auto s0 = __builtin_amdgcn_permlane32_swap(c0[4*g+0], c0[4*g+2], false, false);
      auto s1 = __builtin_amdgcn_permlane32_swap(c0[4*g+1], c0[4*g+3], false, false);
      pa[g][0] = s0[0]; pa[g][2] = s0[1]; pa[g][1] = s1[0]; pa[g][3] = s1[1];
      auto t0 = __builtin_amdgcn_permlane32_swap(c1[4*g+0], c1[4*g+2], false, false);
      auto t1 = __builtin_amdgcn_permlane32_swap(c1[4*g+1], c1[4*g+3], false, false);
      pa[2+g][0] = t0[0]; pa[2+g][2] = t0[1]; pa[2+g][1] = t1[0]; pa[2+g][3] = t1[1];
    }
#else
    #pragma unroll
    for (int half = 0; half < 2; ++half) {
      {
        u32 x0 = c0[half*4+0], x1 = c0[half*4+1], y0 = c0[half*4+2], y1 = c0[half*4+3];
        u32 X0 = __shfl_xor((int)x0, 32), X1 = __shfl_xor((int)x1, 32);
        u32 Y0 = __shfl_xor((int)y0, 32), Y1 = __shfl_xor((int)y1, 32);
        pa[half][0] = hi ? Y0 : x0; pa[half][1] = hi ? Y1 : x1;
        pa[half][2] = hi ? y0 : X0; pa[half][3] = hi ? y1 : X1;
      }
      {
        u32 x0 = c1[half*4+0], x1 = c1[half*4+1], y0 = c1[half*4+2], y1 = c1[half*4+3];
        u32 X0 = __shfl_xor((int)x0, 32), X1 = __shfl_xor((int)x1, 32);
        u32 Y0 = __shfl_xor((int)y0, 32), Y1 = __shfl_xor((int)y1, 32);
        pa[2+half][0] = hi ? Y0 : x0; pa[2+half][1] = hi ? Y1 : x1;
        pa[2+half][2] = hi ? y0 : X0; pa[2+half][3] = hi ? y1 : X1;
      }
    }
#endif

    // ---- PV (+ row-sum via ones-B): acc rows = q (C layout), cols = d
    {
      const int rb0 = l31 * 64, rb1 = (32 + l31) * 64;
      const int r7 = l31 & 7;
      __builtin_amdgcn_s_setprio(1);
      #pragma unroll
      for (int ks = 0; ks < 4; ++ks) {
        u32x4 pw = {pa[ks][0], pa[ks][1], pa[ks][2], pa[ks][3]};
        bf16x8 paf = __builtin_bit_cast(bf16x8, pw);
        const int chv = ((2 * ks + hi) ^ r7) * 8;
        bf16x8 vf0 = *(const bf16x8*)(VL + rb0 + chv);
        bf16x8 vf1 = *(const bf16x8*)(VL + rb1 + chv);
        acc0 = __builtin_amdgcn_mfma_f32_32x32x16_bf16(paf, vf0, acc0, 0, 0, 0);
        acc1 = __builtin_amdgcn_mfma_f32_32x32x16_bf16(paf, vf1, acc1, 0, 0, 0);
        accl = __builtin_amdgcn_mfma_f32_32x32x16_bf16(paf, ones, accl, 0, 0, 0);
      }
      __builtin_amdgcn_s_setprio(0);
    }

    asm volatile("s_waitcnt vmcnt(0)" ::: "memory");
    __syncthreads();
  }

  if constexpr (SPLIT == 0) {
    #pragma unroll
    for (int r = 0; r < 16; ++r) {
      const int q = q0 + (r & 3) + 8 * (r >> 2) + 4 * hi;
      u16* op = Oatt + ((size_t)b * S_LEN + q) * DMOD + h * HD;
      const float inv = 1.0f / accl[r];
      op[l31]      = f32_to_bf16(acc0[r] * inv);
      op[32 + l31] = f32_to_bf16(acc1[r] * inv);
    }
  } else {
    // partial: raw acc (fp32) + per-row (m, l)
    if (lane < 32) alds[w][l31] = m_run;   // m is per-q-column; move to C-row domain
    const size_t BHS = (size_t)64 * S_LEN;
    float* opb = Op + ((size_t)kvh * 64 + bh) * S_LEN * HD;
    float2* mlb = Ml + (size_t)kvh * BHS + (size_t)bh * S_LEN;
    #pragma unroll
    for (int r = 0; r < 16; ++r) {
      const int crow = (r & 3) + 8 * (r >> 2) + 4 * hi;
      const int q = q0 + crow;
      float* op = opb + (size_t)q * HD;
      op[l31]      = acc0[r];
      op[32 + l31] = acc1[r];
      if (l31 == 0) mlb[q] = make_float2(alds[w][crow], accl[r]);
    }
  }
}

// ---------------- split-K combine ----------------
__global__ __launch_bounds__(256) void combine_kernel(const float* __restrict__ Op,
                                                      const float2* __restrict__ Ml,
                                                      u16* __restrict__ Oatt) {
  const size_t NR = (size_t)64 * S_LEN;
  int idx = blockIdx.x * 256 + threadIdx.x;   // (row, d-quarter)
  int row = idx >> 2, dq = (idx & 3) * 16;
  int bh = row >> 11, q = row & 2047;
  int b = bh >> 4, h = bh & 15;
  float2 ml0 = Ml[row], ml1 = Ml[NR + row];
  float mm = fmaxf(ml0.x, ml1.x);
  float s0 = fast_exp2(ml0.x - mm);
  float s1 = fast_exp2(ml1.x - mm);
  float inv = 1.0f / (ml0.y * s0 + ml1.y * s1);
  s0 *= inv; s1 *= inv;
  const float4* p0 = (const float4*)(Op + (size_t)row * HD + dq);
  const float4* p1 = (const float4*)(Op + (NR + (size_t)row) * HD + dq);
  u16* op = Oatt + ((size_t)b * S_LEN + q) * DMOD + h * HD + dq;
  #pragma unroll
  for (int i = 0; i < 4; ++i) {
    float4 a = p0[i], c = p1[i];
    ushort4 o;
    o.x = f32_to_bf16(a.x * s0 + c.x * s1);
    o.y = f32_to_bf16(a.y * s0 + c.y * s1);
    o.z = f32_to_bf16(a.z * s0 + c.z * s1);
    o.w = f32_to_bf16(a.w * s0 + c.w * s1);
    *(ushort4*)(op + i * 4) = o;
  }
}

// ---------------- launch ----------------
extern "C" void kernel_launch(void* const* d_in, const int* in_sizes, int n_in,
                              void* d_out, int out_size, void* d_ws, size_t ws_size,
                              hipStream_t stream) {
  const float* Xq = (const float*)d_in[0];
  const float* Xk = (const float*)d_in[1];
  const float* Xv = (const float*)d_in[2];
  const float* Wq = (const float*)d_in[3];
  const float* bq = (const float*)d_in[4];
  const float* Wk = (const float*)d_in[5];
  const float* bk = (const float*)d_in[6];
  const float* Wv = (const float*)d_in[7];
  const float* bv = (const float*)d_in[8];
  const float* Wo = (const float*)d_in[9];
  const float* bo = (const float*)d_in[10];

  u16* Wqb = (u16*)d_ws;
  u16* Wkb = Wqb + (1 << 20);
  u16* Wvb = Wkb + (1 << 20);
  u16* Wob = Wvb + (1 << 20);
  u16* Qb  = Wob + (1 << 20);
  const size_t QKV = (size_t)64 * S_LEN * HD;  // 8388608 elems
  u16* Kb  = Qb + QKV;
  u16* Vt  = Kb + QKV;
  u16* Oat = Vt + QKV;
  float*  Opart = (float*)(Oat + (size_t)NB * S_LEN * DMOD);
  float2* Ml    = (float2*)(Opart + (size_t)2 * 64 * S_LEN * HD);
  const size_t NEED = (size_t)((char*)(Ml + (size_t)2 * 64 * S_LEN) - (char*)d_ws);
  const bool split = ws_size >= NEED;

  convert4_kernel<<<dim3(1024, 4), 256, 0, stream>>>(Wq, Wk, Wv, Wo, Wqb, Wkb, Wvb, Wob);

  dim3 gg(16, 8, 4);
  gemm_tpl<0><<<gg, 256, 0, stream>>>(Xq, Wqb, bq, Qb, 0.125f * 1.4426950408889634f);
  gemm_tpl<0><<<gg, 256, 0, stream>>>(Xk, Wkb, bk, Kb, 1.0f);
  gemm_tpl<1><<<gg, 256, 0, stream>>>(Xv, Wvb, bv, Vt, 1.0f);

  if (split) {
    attn_kernel<1><<<dim3(16, 16, 4), 512, 0, stream>>>(Qb, Kb, Vt, Oat, Opart, Ml);
    combine_kernel<<<2048, 256, 0, stream>>>(Opart, Ml, Oat);
  } else {
    attn_kernel<0><<<dim3(8, 16, 4), 512, 0, stream>>>(Qb, Kb, Vt, Oat, nullptr, nullptr);
  }

  gemm_tpl<2><<<gg, 256, 0, stream>>>(Oat, Wob, bo, d_out, 1.0f);
}

// Round 4
// 244.811 us; speedup vs baseline: 1.3156x; 1.3156x over previous
//
#include <hip/hip_runtime.h>
#include <stdint.h>

#define S_LEN 2048
#define NB    4
#define DMOD  1024
#define NH    16
#define HD    64

typedef float f32x4 __attribute__((ext_vector_type(4)));
typedef float f32x16 __attribute__((ext_vector_type(16)));
typedef short bf16x8 __attribute__((ext_vector_type(8)));
typedef unsigned int u32x4 __attribute__((ext_vector_type(4)));
typedef unsigned short u16;
typedef unsigned int u32;

__device__ __forceinline__ u16 f32_to_bf16(float f) {
  union { float f; unsigned int u; } v; v.f = f;
  unsigned int r = v.u + 0x7fffu + ((v.u >> 16) & 1u);  // RNE
  return (u16)(r >> 16);
}

__device__ __forceinline__ float fast_exp2(float x) {
#if __has_builtin(__builtin_amdgcn_exp2f)
  return __builtin_amdgcn_exp2f(x);
#else
  return exp2f(x);
#endif
}

typedef __attribute__((address_space(1))) const unsigned int gu32;
typedef __attribute__((address_space(3))) unsigned int lu32;
__device__ __forceinline__ void async_copy16(const void* g, void* l) {
  __builtin_amdgcn_global_load_lds((gu32*)g, (lu32*)l, 16, 0, 0);
}

// ---------------- fp32 -> bf16 weight conversion (4 weights, 1 launch) ----
__global__ __launch_bounds__(256) void convert4_kernel(const float* __restrict__ w0,
                                                       const float* __restrict__ w1,
                                                       const float* __restrict__ w2,
                                                       const float* __restrict__ w3,
                                                       u16* __restrict__ o0, u16* __restrict__ o1,
                                                       u16* __restrict__ o2, u16* __restrict__ o3) {
  const float* in; u16* out;
  switch (blockIdx.y) {
    case 0: in = w0; out = o0; break;
    case 1: in = w1; out = o1; break;
    case 2: in = w2; out = o2; break;
    default: in = w3; out = o3; break;
  }
  int i = (blockIdx.x * 256 + threadIdx.x) * 4;
  float4 v = *(const float4*)(in + i);
  ushort4 o;
  o.x = f32_to_bf16(v.x); o.y = f32_to_bf16(v.y);
  o.z = f32_to_bf16(v.z); o.w = f32_to_bf16(v.w);
  *(ushort4*)(out + i) = o;
}

// ---------------- fused QKV projection GEMM ----------------
// z = which*4 + bz ; which: 0=Q (scaled, [bh][s][dk]), 1=K (swizzled [bh][s][dk']),
// 2=V (transposed+swizzled [bh][dk][s']).
// K row-s swizzle:   dk' = (((dk>>2) ^ (s&15))<<2) | (dk&3)      (8B chunks)
// V row-dk swizzle:  s'  = (s&~63) | ((((s>>2)&15) ^ (dk&15))<<2) | (s&3)
__global__ __launch_bounds__(256) void gemm_qkv(const float* __restrict__ Xq,
                                                const float* __restrict__ Xk,
                                                const float* __restrict__ Xv,
                                                const u16* __restrict__ Wqb,
                                                const u16* __restrict__ Wkb,
                                                const u16* __restrict__ Wvb,
                                                const float* __restrict__ bq,
                                                const float* __restrict__ bk,
                                                const float* __restrict__ bv,
                                                u16* __restrict__ Qo,
                                                u16* __restrict__ Ko,
                                                u16* __restrict__ Vo,
                                                float qscale) {
  __shared__ u16 a_lds[128 * 32];
  __shared__ u16 b_lds[128 * 32];
  const int tid  = threadIdx.x;
  const int wid  = tid >> 6;
  const int lane = tid & 63;
  const int wm = wid >> 1, wn = wid & 1;
  const int which = blockIdx.z >> 2;
  const int bz = blockIdx.z & 3;
  const int m0 = blockIdx.x * 128;
  const int n0 = blockIdx.y * 128;

  const float* A  = (which == 0) ? Xq : (which == 1) ? Xk : Xv;
  const u16* Bw   = (which == 0) ? Wqb : (which == 1) ? Wkb : Wvb;
  const float* bias = (which == 0) ? bq : (which == 1) ? bk : bv;

  f32x4 acc[4][4] = {};

  for (int kt = 0; kt < 32; ++kt) {
    const int k0 = kt * 32;
    __syncthreads();
    #pragma unroll
    for (int i = 0; i < 2; ++i) {
      int row = wid * 32 + i * 16 + (lane >> 2);
      int sc  = (lane & 3) ^ ((row >> 1) & 3);
      const u16* src = Bw + (size_t)(n0 + row) * 1024 + k0 + sc * 8;
      async_copy16(src, b_lds + wid * 1024 + i * 512);
    }
    {
      int row = tid >> 1, half = tid & 1;
      const float* src = A + ((size_t)(m0 + row) * NB + bz) * 1024 + k0 + half * 16;
      u16 tmp[16];
      #pragma unroll
      for (int i = 0; i < 4; ++i) {
        float4 v = *(const float4*)(src + i * 4);
        tmp[i*4+0] = f32_to_bf16(v.x); tmp[i*4+1] = f32_to_bf16(v.y);
        tmp[i*4+2] = f32_to_bf16(v.z); tmp[i*4+3] = f32_to_bf16(v.w);
      }
      #pragma unroll
      for (int c = 0; c < 2; ++c) {
        int chunk = half * 2 + c;
        int slot  = chunk ^ ((row >> 1) & 3);
        *(int4*)(a_lds + row * 32 + slot * 8) = *(const int4*)(tmp + c * 8);
      }
    }
    asm volatile("s_waitcnt vmcnt(0)" ::: "memory");
    __syncthreads();

    bf16x8 af[4], bfr[4];
    #pragma unroll
    for (int mi = 0; mi < 4; ++mi) {
      int row = wm * 64 + mi * 16 + (lane & 15);
      int ch  = (lane >> 4) ^ ((row >> 1) & 3);
      af[mi] = *(const bf16x8*)(a_lds + row * 32 + ch * 8);
    }
    #pragma unroll
    for (int ni = 0; ni < 4; ++ni) {
      int row = wn * 64 + ni * 16 + (lane & 15);
      int ch  = (lane >> 4) ^ ((row >> 1) & 3);
      bfr[ni] = *(const bf16x8*)(b_lds + row * 32 + ch * 8);
    }
    #pragma unroll
    for (int mi = 0; mi < 4; ++mi)
      #pragma unroll
      for (int ni = 0; ni < 4; ++ni)
        acc[mi][ni] = __builtin_amdgcn_mfma_f32_16x16x32_bf16(af[mi], bfr[ni], acc[mi][ni], 0, 0, 0);
  }

  // epilogue: C row = (lane>>4)*4 + r, col = lane&15
  #pragma unroll
  for (int ni = 0; ni < 4; ++ni) {
    int n = n0 + wn * 64 + ni * 16 + (lane & 15);
    float bv = bias[n];
    int hh = n >> 6, dk = n & 63;
    size_t baseQ = (size_t)(bz * NH + hh) * S_LEN;
    #pragma unroll
    for (int mi = 0; mi < 4; ++mi) {
      int sbase = m0 + wm * 64 + mi * 16 + ((lane >> 4) << 2);
      if (which == 0) {
        #pragma unroll
        for (int r = 0; r < 4; ++r)
          Qo[(baseQ + sbase + r) * HD + dk] = f32_to_bf16((acc[mi][ni][r] + bv) * qscale);
      } else if (which == 1) {
        #pragma unroll
        for (int r = 0; r < 4; ++r) {
          int s = sbase + r;
          int dkp = (((dk >> 2) ^ (s & 15)) << 2) | (dk & 3);
          Ko[(baseQ + s) * HD + dkp] = f32_to_bf16(acc[mi][ni][r] + bv);
        }
      } else {
        int cc = (sbase >> 2) & 15;
        int sp = (sbase & ~63) | (((cc ^ (dk & 15)) << 2));
        size_t idx = ((size_t)(bz * NH + hh) * HD + dk) * S_LEN + sp;
        ushort4 o4;
        o4.x = f32_to_bf16(acc[mi][ni][0] + bv);
        o4.y = f32_to_bf16(acc[mi][ni][1] + bv);
        o4.z = f32_to_bf16(acc[mi][ni][2] + bv);
        o4.w = f32_to_bf16(acc[mi][ni][3] + bv);
        *(ushort4*)(Vo + idx) = o4;
      }
    }
  }
}

// ---------------- output projection GEMM (A bf16 [NB][S][D] -> fp32) ------
__global__ __launch_bounds__(256) void gemm_out(const u16* __restrict__ Ab,
                                                const u16* __restrict__ Bw,
                                                const float* __restrict__ bias,
                                                float* __restrict__ outp) {
  __shared__ u16 a_lds[128 * 32];
  __shared__ u16 b_lds[128 * 32];
  const int tid  = threadIdx.x;
  const int wid  = tid >> 6;
  const int lane = tid & 63;
  const int wm = wid >> 1, wn = wid & 1;
  const int bz = blockIdx.z;
  const int m0 = blockIdx.x * 128;
  const int n0 = blockIdx.y * 128;

  f32x4 acc[4][4] = {};

  for (int kt = 0; kt < 32; ++kt) {
    const int k0 = kt * 32;
    __syncthreads();
    #pragma unroll
    for (int i = 0; i < 2; ++i) {
      int row = wid * 32 + i * 16 + (lane >> 2);
      int sc  = (lane & 3) ^ ((row >> 1) & 3);
      async_copy16(Bw + (size_t)(n0 + row) * 1024 + k0 + sc * 8, b_lds + wid * 1024 + i * 512);
      async_copy16(Ab + ((size_t)bz * S_LEN + m0 + row) * 1024 + k0 + sc * 8, a_lds + wid * 1024 + i * 512);
    }
    asm volatile("s_waitcnt vmcnt(0)" ::: "memory");
    __syncthreads();

    bf16x8 af[4], bfr[4];
    #pragma unroll
    for (int mi = 0; mi < 4; ++mi) {
      int row = wm * 64 + mi * 16 + (lane & 15);
      int ch  = (lane >> 4) ^ ((row >> 1) & 3);
      af[mi] = *(const bf16x8*)(a_lds + row * 32 + ch * 8);
    }
    #pragma unroll
    for (int ni = 0; ni < 4; ++ni) {
      int row = wn * 64 + ni * 16 + (lane & 15);
      int ch  = (lane >> 4) ^ ((row >> 1) & 3);
      bfr[ni] = *(const bf16x8*)(b_lds + row * 32 + ch * 8);
    }
    #pragma unroll
    for (int mi = 0; mi < 4; ++mi)
      #pragma unroll
      for (int ni = 0; ni < 4; ++ni)
        acc[mi][ni] = __builtin_amdgcn_mfma_f32_16x16x32_bf16(af[mi], bfr[ni], acc[mi][ni], 0, 0, 0);
  }

  #pragma unroll
  for (int ni = 0; ni < 4; ++ni) {
    int n = n0 + wn * 64 + ni * 16 + (lane & 15);
    float bv = bias[n];
    #pragma unroll
    for (int mi = 0; mi < 4; ++mi) {
      int sbase = m0 + wm * 64 + mi * 16 + ((lane >> 4) << 2);
      #pragma unroll
      for (int r = 0; r < 4; ++r)
        outp[((size_t)(sbase + r) * NB + bz) * 1024 + n] = acc[mi][ni][r] + bv;
    }
  }
}

// ---------------- flash attention, 8-wave 32x32 swapped-QK ----------------
// Qb: [bh][s][dk] bf16 (pre-scaled). Kb: row-swizzled. Vt: [bh][dk][s'] swizzled.
// Conflict-free ds_read_b64 pairs; l as scalar in q-domain; no split-K.
__global__ __launch_bounds__(512, 4) void attn_kernel(const u16* __restrict__ Qb,
                                                      const u16* __restrict__ Kb,
                                                      const u16* __restrict__ Vt,
                                                      u16* __restrict__ Oatt) {
  __shared__ u16 kbuf[2][64 * 64];
  __shared__ u16 vbuf[2][64 * 64];
  __shared__ float alds[8][32];
  const int tid = threadIdx.x;
  const int w = tid >> 6, lane = tid & 63;
  const int hi = lane >> 5, l31 = lane & 31;
  const int h = blockIdx.y, b = blockIdx.z;
  const int bh = b * NH + h;
  const int q0 = blockIdx.x * 256 + w * 32;
  const int key = l31 & 15;                 // swizzle key (rows r and r+32 share it)

  bf16x8 qf[4];
  {
    const u16* qp = Qb + ((size_t)bh * S_LEN + q0 + l31) * HD + hi * 8;
    #pragma unroll
    for (int s = 0; s < 4; ++s) qf[s] = *(const bf16x8*)(qp + s * 16);
  }

  f32x16 acc0 = {}, acc1 = {};
  float m_run = -1e30f, l_run = 0.0f;

  const int rl = w * 8 + (lane >> 3);
  const u16* ksrc = Kb + ((size_t)bh * S_LEN + rl) * HD + (lane & 7) * 8;
  const u16* vsrc = Vt + ((size_t)bh * HD + rl) * S_LEN + (lane & 7) * 8;

  async_copy16(ksrc, &kbuf[0][w * 512]);
  async_copy16(vsrc, &vbuf[0][w * 512]);
  asm volatile("s_waitcnt vmcnt(0)" ::: "memory");
  __syncthreads();

  for (int kb = 0; kb < 32; ++kb) {
    const int cur = kb & 1;
    if (kb + 1 < 32) {
      async_copy16(ksrc + (size_t)(kb + 1) * 64 * HD, &kbuf[cur ^ 1][w * 512]);
      async_copy16(vsrc + (kb + 1) * 64, &vbuf[cur ^ 1][w * 512]);
    }
    const u16* KL = kbuf[cur];
    const u16* VL = vbuf[cur];

    // ---- QK^T (swapped): D[k][q], col q = lane&31; conflict-free b64 pairs
    f32x16 pk0 = {}, pk1 = {};
    __builtin_amdgcn_s_setprio(1);
    #pragma unroll
    for (int s = 0; s < 4; ++s) {
      const int c0 = 4 * s + 2 * hi;               // logical 8B chunk
      const int p0 = (c0 ^ key) * 4;               // u16 offset of slot
      const int p1 = ((c0 + 1) ^ key) * 4;
      uint2 a0 = *(const uint2*)(KL + l31 * 64 + p0);
      uint2 a1 = *(const uint2*)(KL + l31 * 64 + p1);
      uint2 b0 = *(const uint2*)(KL + (32 + l31) * 64 + p0);
      uint2 b1 = *(const uint2*)(KL + (32 + l31) * 64 + p1);
      u32x4 kw0 = {a0.x, a0.y, a1.x, a1.y};
      u32x4 kw1 = {b0.x, b0.y, b1.x, b1.y};
      pk0 = __builtin_amdgcn_mfma_f32_32x32x16_bf16(__builtin_bit_cast(bf16x8, kw0), qf[s], pk0, 0, 0, 0);
      pk1 = __builtin_amdgcn_mfma_f32_32x32x16_bf16(__builtin_bit_cast(bf16x8, kw1), qf[s], pk1, 0, 0, 0);
    }
    __builtin_amdgcn_s_setprio(0);

    // ---- online softmax, in-register (q = lane&31 domain)
    float t8[8];
    #pragma unroll
    for (int r = 0; r < 8; ++r)
      t8[r] = fmaxf(fmaxf(pk0[r], pk0[r + 8]), fmaxf(pk1[r], pk1[r + 8]));
    float pm = fmaxf(fmaxf(fmaxf(t8[0], t8[1]), fmaxf(t8[2], t8[3])),
                     fmaxf(fmaxf(t8[4], t8[5]), fmaxf(t8[6], t8[7])));
#if __has_builtin(__builtin_amdgcn_permlane32_swap)
    {
      u32 pmu = __builtin_bit_cast(u32, pm);
      auto sw = __builtin_amdgcn_permlane32_swap(pmu, pmu, false, false);
      float po = __builtin_bit_cast(float, hi ? sw[0] : sw[1]);
      pm = fmaxf(pm, po);
    }
#else
    pm = fmaxf(pm, __shfl_xor(pm, 32));
#endif

    if (!__all(pm <= m_run + 8.0f)) {   // defer-max: rescale is rare
      float mn = fmaxf(m_run, pm);
      float al = fast_exp2(m_run - mn);
      m_run = mn;
      l_run *= al;
      if (lane < 32) alds[w][l31] = al;
      #pragma unroll
      for (int r = 0; r < 16; ++r) {
        float av = alds[w][(r & 3) + 8 * (r >> 2) + 4 * hi];
        acc0[r] *= av; acc1[r] *= av;
      }
    }
    #pragma unroll
    for (int r = 0; r < 16; ++r) {
      pk0[r] = fast_exp2(pk0[r] - m_run);
      pk1[r] = fast_exp2(pk1[r] - m_run);
    }

    // ---- row-sum (q-domain scalar l): VALU adds + one cross-half swap
    float rs = 0.0f;
    #pragma unroll
    for (int r = 0; r < 16; ++r) rs += pk0[r] + pk1[r];
#if __has_builtin(__builtin_amdgcn_permlane32_swap)
    {
      u32 ru = __builtin_bit_cast(u32, rs);
      auto sw = __builtin_amdgcn_permlane32_swap(ru, ru, false, false);
      rs += __builtin_bit_cast(float, hi ? sw[0] : sw[1]);
    }
#else
    rs += __shfl_xor(rs, 32);
#endif
    l_run += rs;

    // ---- P -> bf16 (cvt_pk) then per-half A-frag build + PV MFMA
    u32 c0v[8], c1v[8];
    #pragma unroll
    for (int i = 0; i < 8; ++i) {
      float a0 = pk0[2 * i], b0 = pk0[2 * i + 1];
      float a1 = pk1[2 * i], b1 = pk1[2 * i + 1];
      asm("v_cvt_pk_bf16_f32 %0, %1, %2" : "=v"(c0v[i]) : "v"(a0), "v"(b0));
      asm("v_cvt_pk_bf16_f32 %0, %1, %2" : "=v"(c1v[i]) : "v"(a1), "v"(b1));
    }

    __builtin_amdgcn_s_setprio(1);
    #pragma unroll
    for (int g = 0; g < 2; ++g) {
      u32 pa0[4], pa1[4];
#if __has_builtin(__builtin_amdgcn_permlane32_swap)
      {
        auto s0 = __builtin_amdgcn_permlane32_swap(c0v[4*g+0], c0v[4*g+2], false, false);
        auto s1 = __builtin_amdgcn_permlane32_swap(c0v[4*g+1], c0v[4*g+3], false, false);
        pa0[0] = s0[0]; pa0[2] = s0[1]; pa0[1] = s1[0]; pa0[3] = s1[1];
        auto t0 = __builtin_amdgcn_permlane32_swap(c1v[4*g+0], c1v[4*g+2], false, false);
        auto t1 = __builtin_amdgcn_permlane32_swap(c1v[4*g+1], c1v[4*g+3], false, false);
        pa1[0] = t0[0]; pa1[2] = t0[1]; pa1[1] = t1[0]; pa1[3] = t1[1];
      }
#else
      {
        u32 x0 = c0v[4*g+0], x1 = c0v[4*g+1], y0 = c0v[4*g+2], y1 = c0v[4*g+3];
        u32 X0 = __shfl_xor((int)x0, 32), X1 = __shfl_xor((int)x1, 32);
        u32 Y0 = __shfl_xor((int)y0, 32), Y1 = __shfl_xor((int)y1, 32);
        pa0[0] = hi ? Y0 : x0; pa0[1] = hi ? Y1 : x1;
        pa0[2] = hi ? y0 : X0; pa0[3] = hi ? y1 : X1;
        x0 = c1v[4*g+0]; x1 = c1v[4*g+1]; y0 = c1v[4*g+2]; y1 = c1v[4*g+3];
        X0 = __shfl_xor((int)x0, 32); X1 = __shfl_xor((int)x1, 32);
        Y0 = __shfl_xor((int)y0, 32); Y1 = __shfl_xor((int)y1, 32);
        pa1[0] = hi ? Y0 : x0; pa1[1] = hi ? Y1 : x1;
        pa1[2] = hi ? y0 : X0; pa1[3] = hi ? y1 : X1;
      }
#endif
      // ks = g (from c0 block) and ks = 2+g (from c1 block)
      #pragma unroll
      for (int t = 0; t < 2; ++t) {
        const int ks = t == 0 ? g : 2 + g;
        u32x4 pw = t == 0 ? (u32x4){pa0[0], pa0[1], pa0[2], pa0[3]}
                          : (u32x4){pa1[0], pa1[1], pa1[2], pa1[3]};
        bf16x8 paf = __builtin_bit_cast(bf16x8, pw);
        const int c0c = 4 * ks + 2 * hi;
        const int p0 = (c0c ^ key) * 4;
        const int p1 = ((c0c + 1) ^ key) * 4;
        uint2 va0 = *(const uint2*)(VL + l31 * 64 + p0);
        uint2 va1 = *(const uint2*)(VL + l31 * 64 + p1);
        uint2 vb0 = *(const uint2*)(VL + (32 + l31) * 64 + p0);
        uint2 vb1 = *(const uint2*)(VL + (32 + l31) * 64 + p1);
        u32x4 vw0 = {va0.x, va0.y, va1.x, va1.y};
        u32x4 vw1 = {vb0.x, vb0.y, vb1.x, vb1.y};
        acc0 = __builtin_amdgcn_mfma_f32_32x32x16_bf16(paf, __builtin_bit_cast(bf16x8, vw0), acc0, 0, 0, 0);
        acc1 = __builtin_amdgcn_mfma_f32_32x32x16_bf16(paf, __builtin_bit_cast(bf16x8, vw1), acc1, 0, 0, 0);
      }
    }
    __builtin_amdgcn_s_setprio(0);

    asm volatile("s_waitcnt vmcnt(0)" ::: "memory");
    __syncthreads();
  }

  // ---- epilogue: broadcast l to C-row domain, O = acc / l
  if (lane < 32) alds[w][l31] = l_run;
  #pragma unroll
  for (int r = 0; r < 16; ++r) {
    const int crow = (r & 3) + 8 * (r >> 2) + 4 * hi;
    const int q = q0 + crow;
    u16* op = Oatt + ((size_t)b * S_LEN + q) * DMOD + h * HD;
    const float inv = 1.0f / alds[w][crow];
    op[l31]      = f32_to_bf16(acc0[r] * inv);
    op[32 + l31] = f32_to_bf16(acc1[r] * inv);
  }
}

// ---------------- launch ----------------
extern "C" void kernel_launch(void* const* d_in, const int* in_sizes, int n_in,
                              void* d_out, int out_size, void* d_ws, size_t ws_size,
                              hipStream_t stream) {
  const float* Xq = (const float*)d_in[0];
  const float* Xk = (const float*)d_in[1];
  const float* Xv = (const float*)d_in[2];
  const float* Wq = (const float*)d_in[3];
  const float* bq = (const float*)d_in[4];
  const float* Wk = (const float*)d_in[5];
  const float* bk = (const float*)d_in[6];
  const float* Wv = (const float*)d_in[7];
  const float* bv = (const float*)d_in[8];
  const float* Wo = (const float*)d_in[9];
  const float* bo = (const float*)d_in[10];

  u16* Wqb = (u16*)d_ws;
  u16* Wkb = Wqb + (1 << 20);
  u16* Wvb = Wkb + (1 << 20);
  u16* Wob = Wvb + (1 << 20);
  u16* Qb  = Wob + (1 << 20);
  const size_t QKV = (size_t)64 * S_LEN * HD;  // 8388608 elems
  u16* Kb  = Qb + QKV;
  u16* Vt  = Kb + QKV;
  u16* Oat = Vt + QKV;

  convert4_kernel<<<dim3(1024, 4), 256, 0, stream>>>(Wq, Wk, Wv, Wo, Wqb, Wkb, Wvb, Wob);

  // Q pre-scaled by (1/sqrt(64)) * log2(e) so softmax runs in exp2 domain
  gemm_qkv<<<dim3(16, 8, 12), 256, 0, stream>>>(Xq, Xk, Xv, Wqb, Wkb, Wvb,
                                                bq, bk, bv, Qb, Kb, Vt,
                                                0.125f * 1.4426950408889634f);

  attn_kernel<<<dim3(8, 16, 4), 512, 0, stream>>>(Qb, Kb, Vt, Oat);

  gemm_out<<<dim3(16, 8, 4), 256, 0, stream>>>(Oat, Wob, bo, (float*)d_out);
}